// Round 7
// baseline (801.066 us; speedup 1.0000x reference)
//
#include <hip/hip_runtime.h>
#include <hip/hip_bf16.h>
#include <math.h>

// ConformerBlock on MI355X. B=4, S=4096, D=512, H=8, Hd=64, CTX=128, FFN=2048, KS=31.
// fp32 inputs/outputs. bf16 MFMA GEMMs (128x128 tile + global_load_lds + XCD swizzle,
// split-K for K=2048), fused QKV, MFMA flash attention, tiled depthwise conv.

using bf16 = __hip_bfloat16;
typedef __bf16 bf16x8_t __attribute__((ext_vector_type(8)));
typedef float f32x4_t __attribute__((ext_vector_type(4)));

static __device__ __forceinline__ float bf2f(bf16 v) { return __bfloat162float(v); }
static __device__ __forceinline__ bf16 f2bf(float v) { return __float2bfloat16(v); }

#define GLOAD_LDS16(g, l)                                                            \
    __builtin_amdgcn_global_load_lds((const __attribute__((address_space(1))) void*)(g), \
                                     (__attribute__((address_space(3))) void*)(l), 16, 0, 0)

// ---------------- fp32 [K][N] -> bf16 transposed [N][K] ----------------
__global__ __launch_bounds__(256) void k_f2bt(const float* __restrict__ in, bf16* __restrict__ out,
                                              int K, int N) {
    __shared__ float t[32][33];
    int c = threadIdx.x & 31, r0 = threadIdx.x >> 5;
    int kb = blockIdx.y * 32, nb = blockIdx.x * 32;
#pragma unroll
    for (int i = 0; i < 4; ++i)
        t[r0 + i * 8][c] = in[(size_t)(kb + r0 + i * 8) * N + nb + c];
    __syncthreads();
#pragma unroll
    for (int i = 0; i < 4; ++i)
        out[(size_t)(nb + r0 + i * 8) * K + kb + c] = f2bf(t[c][r0 + i * 8]);
}

// ---------------- LayerNorm: fp32 in -> bf16 (or fp32) out, one wave per row ----------------
template <bool BF16OUT>
__global__ __launch_bounds__(64) void k_ln(const float* __restrict__ x, const float* __restrict__ g,
                                           const float* __restrict__ b, void* __restrict__ outp) {
    int row = blockIdx.x, t = threadIdx.x;
    const float* xr = x + (size_t)row * 512 + t * 8;
    float4 v0 = *(const float4*)xr;
    float4 v1 = *(const float4*)(xr + 4);
    float vals[8] = {v0.x, v0.y, v0.z, v0.w, v1.x, v1.y, v1.z, v1.w};
    float s = 0.f, ss = 0.f;
#pragma unroll
    for (int j = 0; j < 8; ++j) { s += vals[j]; ss += vals[j] * vals[j]; }
#pragma unroll
    for (int o = 32; o > 0; o >>= 1) { s += __shfl_xor(s, o, 64); ss += __shfl_xor(ss, o, 64); }
    float mean = s * (1.0f / 512.0f);
    float var  = ss * (1.0f / 512.0f) - mean * mean;
    float r = rsqrtf(var + 1e-5f);
    float4 g0 = *(const float4*)(g + t * 8);
    float4 g1 = *(const float4*)(g + t * 8 + 4);
    float4 b0 = *(const float4*)(b + t * 8);
    float4 b1 = *(const float4*)(b + t * 8 + 4);
    float gv[8] = {g0.x, g0.y, g0.z, g0.w, g1.x, g1.y, g1.z, g1.w};
    float bv[8] = {b0.x, b0.y, b0.z, b0.w, b1.x, b1.y, b1.z, b1.w};
    float ov[8];
#pragma unroll
    for (int j = 0; j < 8; ++j) ov[j] = (vals[j] - mean) * r * gv[j] + bv[j];
    if (BF16OUT) {
        union { uint4 u; bf16 h[8]; } oo;
#pragma unroll
        for (int j = 0; j < 8; ++j) oo.h[j] = f2bf(ov[j]);
        *(uint4*)((bf16*)outp + (size_t)row * 512 + t * 8) = oo.u;
    } else {
        float* op = (float*)outp + (size_t)row * 512 + t * 8;
        *(float4*)op = make_float4(ov[0], ov[1], ov[2], ov[3]);
        *(float4*)(op + 4) = make_float4(ov[4], ov[5], ov[6], ov[7]);
    }
}

// ---------------- GEMM: C = A[M,K] @ Bt[N,K]^T + bias, 128x128 tile, XCD swizzle ----------------
// 1D grid of nbx*128 blocks; same-A-row-tile blocks land on consecutive slots of one XCD.
// MODE 0: bf16 store. MODE 1: exact GELU -> bf16. MODE 2: fp32 out += scale*(acc+bias).
// MODE 3: QKV scatter (col/512 selects q/k/v buffer and bias). MODE 4: split-K (gridDim.y=2),
//         fp32 atomicAdd of scale*(acc + bias at kz==0).
template <int MODE>
__global__ __launch_bounds__(256) void k_gemm(const bf16* __restrict__ A, const bf16* __restrict__ Bt,
                                              const float* __restrict__ bias, void* __restrict__ outp,
                                              int M, int N, int K, float scale,
                                              const float* __restrict__ b2, const float* __restrict__ b3,
                                              int nbx) {
    __shared__ __align__(16) bf16 As[128 * 32];
    __shared__ __align__(16) bf16 Bs[128 * 32];
    int id = blockIdx.x;
    int xcd = id & 7, slot = id >> 3;
    int nbyg = (gridDim.x / nbx) >> 3;          // by-groups per XCD
    int bxi = slot % nbx;
    int byi = slot / nbx + xcd * nbyg;
    int bn = bxi * 128, bm = byi * 128;
    int tid = threadIdx.x, w = tid >> 6, l = tid & 63;
    int l15 = l & 15, quad = l >> 4;
    int wm = (w >> 1) * 64, wn = (w & 1) * 64;
    f32x4_t acc[4][4] = {};
    int Klen = K, koff = 0;
    if (MODE == 4) { Klen = K >> 1; koff = blockIdx.y * Klen; }
    const bf16* ag = A + (size_t)(bm + w * 32 + (l >> 2)) * K + koff + (l & 3) * 8;
    const bf16* bg = Bt + (size_t)(bn + w * 32 + (l >> 2)) * K + koff + (l & 3) * 8;
    bf16* asl = As + w * 32 * 32;               // wave-uniform LDS bases
    bf16* bsl = Bs + w * 32 * 32;

    for (int k0 = 0; k0 < Klen; k0 += 32) {
        __syncthreads();
#pragma unroll
        for (int j = 0; j < 2; ++j) {
            GLOAD_LDS16(ag + (size_t)j * 16 * K + k0, asl + j * 16 * 32);
            GLOAD_LDS16(bg + (size_t)j * 16 * K + k0, bsl + j * 16 * 32);
        }
        __syncthreads();
        bf16x8_t af[4], bfr[4];
#pragma unroll
        for (int tm = 0; tm < 4; ++tm)
            af[tm] = *(const bf16x8_t*)(As + (wm + tm * 16 + l15) * 32 + quad * 8);
#pragma unroll
        for (int tn = 0; tn < 4; ++tn)
            bfr[tn] = *(const bf16x8_t*)(Bs + (wn + tn * 16 + l15) * 32 + quad * 8);
#pragma unroll
        for (int tm = 0; tm < 4; ++tm)
#pragma unroll
            for (int tn = 0; tn < 4; ++tn)
                acc[tm][tn] = __builtin_amdgcn_mfma_f32_16x16x32_bf16(af[tm], bfr[tn], acc[tm][tn], 0, 0, 0);
    }
#pragma unroll
    for (int tm = 0; tm < 4; ++tm)
#pragma unroll
        for (int tn = 0; tn < 4; ++tn) {
            int gcol = bn + wn + tn * 16 + l15;
            float bv;
            if (MODE == 3) {
                const float* bp = (gcol < 512) ? bias : (gcol < 1024 ? b2 : b3);
                bv = bp[gcol & 511];
            } else if (MODE == 4) {
                bv = (blockIdx.y == 0) ? bias[gcol] : 0.f;
            } else {
                bv = bias[gcol];
            }
#pragma unroll
            for (int r = 0; r < 4; ++r) {
                int grow = bm + wm + tm * 16 + quad * 4 + r;
                float vv = acc[tm][tn][r] + bv;
                if (MODE == 0) {
                    ((bf16*)outp)[(size_t)grow * N + gcol] = f2bf(vv);
                } else if (MODE == 1) {
                    float gl = 0.5f * vv * (1.0f + erff(vv * 0.70710678118654752f));
                    ((bf16*)outp)[(size_t)grow * N + gcol] = f2bf(gl);
                } else if (MODE == 2) {
                    ((float*)outp)[(size_t)grow * N + gcol] += scale * vv;
                } else if (MODE == 3) {
                    bf16* ob = (bf16*)outp + (size_t)(gcol >> 9) * 8388608;
                    ob[(size_t)grow * 512 + (gcol & 511)] = f2bf(vv);
                } else {
                    atomicAdd(&((float*)outp)[(size_t)grow * N + gcol], scale * vv);
                }
            }
        }
}

// ---------------- MFMA flash attention over 384-key windows ----------------
__global__ __launch_bounds__(256) void k_attn(const bf16* __restrict__ q, const bf16* __restrict__ k,
                                              const bf16* __restrict__ v, const float* __restrict__ rel_bias,
                                              bf16* __restrict__ out) {
    __shared__ __align__(16) bf16 Qs[128][72];
    __shared__ __align__(16) bf16 Ks[64][72];
    __shared__ __align__(16) bf16 Vt[64][72];
    __shared__ __align__(16) bf16 Pb[4][32][72];
    __shared__ float relb[257];
    int blk = blockIdx.x;
    int n = blk & 31, h = (blk >> 5) & 7, b = blk >> 8;
    int tid = threadIdx.x, w = tid >> 6, lane = tid & 63;
    int l15 = lane & 15, quad = lane >> 4;
    for (int i = tid; i < 257; i += 256) relb[i] = rel_bias[h * 257 + i];
    {
        const bf16* qg = q + (size_t)(b * 4096 + n * 128) * 512 + h * 64;
#pragma unroll
        for (int i = 0; i < 4; ++i) {
            int slot = tid + 256 * i;
            int row = slot >> 3, col = (slot & 7) * 8;
            *(uint4*)&Qs[row][col] = *(const uint4*)(qg + (size_t)row * 512 + col);
        }
    }
    float m_run[2][4], l_run[2][4];
#pragma unroll
    for (int qt = 0; qt < 2; ++qt)
#pragma unroll
        for (int r = 0; r < 4; ++r) { m_run[qt][r] = -1e30f; l_run[qt][r] = 0.f; }
    f32x4_t Oacc[2][4] = {};
    int kv0 = n * 128 - 128;
    for (int ch = 0; ch < 6; ++ch) {
        int kst = kv0 + ch * 64;
        if (kst < 0 || kst >= 4096) continue;
        __syncthreads();
        {
#pragma unroll
            for (int i = 0; i < 2; ++i) {
                int slot = tid + 256 * i;
                int row = slot >> 3, col = (slot & 7) * 8;
                *(uint4*)&Ks[row][col] = *(const uint4*)(k + (size_t)(b * 4096 + kst + row) * 512 + h * 64 + col);
            }
        }
        {
            int key = tid >> 2, c0 = (tid & 3) * 16;
            union { uint4 u[2]; bf16 hh[16]; } tv;
            const bf16* vg = v + (size_t)(b * 4096 + kst + key) * 512 + h * 64 + c0;
            tv.u[0] = *(const uint4*)vg;
            tv.u[1] = *(const uint4*)(vg + 8);
#pragma unroll
            for (int j = 0; j < 16; ++j) Vt[c0 + j][key] = tv.hh[j];
        }
        __syncthreads();
        bf16x8_t qf[2][2];
#pragma unroll
        for (int qt = 0; qt < 2; ++qt)
#pragma unroll
            for (int ks = 0; ks < 2; ++ks)
                qf[qt][ks] = *(const bf16x8_t*)&Qs[w * 32 + qt * 16 + l15][ks * 32 + quad * 8];
        float sc[2][4][4];
#pragma unroll
        for (int qt = 0; qt < 2; ++qt)
#pragma unroll
            for (int nt = 0; nt < 4; ++nt) {
                f32x4_t a = {};
#pragma unroll
                for (int ks = 0; ks < 2; ++ks) {
                    bf16x8_t kf = *(const bf16x8_t*)&Ks[nt * 16 + l15][ks * 32 + quad * 8];
                    a = __builtin_amdgcn_mfma_f32_16x16x32_bf16(qf[qt][ks], kf, a, 0, 0, 0);
                }
#pragma unroll
                for (int r = 0; r < 4; ++r) sc[qt][nt][r] = a[r];
            }
#pragma unroll
        for (int qt = 0; qt < 2; ++qt)
#pragma unroll
            for (int nt = 0; nt < 4; ++nt)
#pragma unroll
                for (int r = 0; r < 4; ++r) {
                    int qrow = w * 32 + qt * 16 + quad * 4 + r;
                    int rel = ch * 64 + nt * 16 + l15 - 128 - qrow;
                    int idx = rel + 128; idx = idx < 0 ? 0 : (idx > 256 ? 256 : idx);
                    float s = sc[qt][nt][r] * 0.125f + relb[idx];
                    sc[qt][nt][r] = (rel >= -128 && rel <= 128) ? s : -INFINITY;
                }
        float al[2][4];
#pragma unroll
        for (int qt = 0; qt < 2; ++qt)
#pragma unroll
            for (int r = 0; r < 4; ++r) {
                float mx = fmaxf(fmaxf(sc[qt][0][r], sc[qt][1][r]), fmaxf(sc[qt][2][r], sc[qt][3][r]));
#pragma unroll
                for (int mk = 1; mk <= 8; mk <<= 1) mx = fmaxf(mx, __shfl_xor(mx, mk, 64));
                float mn = fmaxf(m_run[qt][r], mx);
                float a = __expf(m_run[qt][r] - mn);
                float ps = 0.f;
#pragma unroll
                for (int nt = 0; nt < 4; ++nt) {
                    float p = __expf(sc[qt][nt][r] - mn);
                    sc[qt][nt][r] = p;
                    ps += p;
                }
#pragma unroll
                for (int mk = 1; mk <= 8; mk <<= 1) ps += __shfl_xor(ps, mk, 64);
                l_run[qt][r] = l_run[qt][r] * a + ps;
                m_run[qt][r] = mn;
                al[qt][r] = a;
            }
#pragma unroll
        for (int qt = 0; qt < 2; ++qt)
#pragma unroll
            for (int nt = 0; nt < 4; ++nt)
#pragma unroll
                for (int r = 0; r < 4; ++r)
                    Pb[w][qt * 16 + quad * 4 + r][nt * 16 + l15] = f2bf(sc[qt][nt][r]);
        __syncthreads();
#pragma unroll
        for (int qt = 0; qt < 2; ++qt) {
#pragma unroll
            for (int dt = 0; dt < 4; ++dt)
#pragma unroll
                for (int r = 0; r < 4; ++r)
                    Oacc[qt][dt][r] *= al[qt][r];
            bf16x8_t pf[2];
#pragma unroll
            for (int ks = 0; ks < 2; ++ks)
                pf[ks] = *(const bf16x8_t*)&Pb[w][qt * 16 + l15][ks * 32 + quad * 8];
#pragma unroll
            for (int dt = 0; dt < 4; ++dt) {
                f32x4_t a = Oacc[qt][dt];
#pragma unroll
                for (int ks = 0; ks < 2; ++ks) {
                    bf16x8_t vf = *(const bf16x8_t*)&Vt[dt * 16 + l15][ks * 32 + quad * 8];
                    a = __builtin_amdgcn_mfma_f32_16x16x32_bf16(pf[ks], vf, a, 0, 0, 0);
                }
                Oacc[qt][dt] = a;
            }
        }
    }
#pragma unroll
    for (int qt = 0; qt < 2; ++qt)
#pragma unroll
        for (int r = 0; r < 4; ++r) {
            float inv = 1.f / l_run[qt][r];
            int row = n * 128 + w * 32 + qt * 16 + quad * 4 + r;
#pragma unroll
            for (int dt = 0; dt < 4; ++dt)
                out[(size_t)(b * 4096 + row) * 512 + h * 64 + dt * 16 + l15] = f2bf(Oacc[qt][dt][r] * inv);
        }
}

// ---------------- GLU: [16384,1024] -> [16384,512], bf16 ----------------
__global__ __launch_bounds__(256) void k_glu(const bf16* __restrict__ h, bf16* __restrict__ out) {
    int idx = blockIdx.x * 256 + threadIdx.x;
    int m = idx >> 9, c = idx & 511;
    float a = bf2f(h[(size_t)m * 1024 + c]);
    float g = bf2f(h[(size_t)m * 1024 + c + 512]);
    out[idx] = f2bf(a / (1.f + __expf(-g)));
}

// ---------------- tiled depthwise conv (KS=31) + BN + SiLU ----------------
__global__ __launch_bounds__(256) void k_conv(const bf16* __restrict__ in, const float* __restrict__ w,
                                              const float* __restrict__ wb, const float* __restrict__ bg,
                                              const float* __restrict__ bb2, const float* __restrict__ bm,
                                              const float* __restrict__ bvv, bf16* __restrict__ out) {
    __shared__ float wl[64 * 31];
    int d0 = blockIdx.x * 64, s0 = blockIdx.y * 64, b = blockIdx.z;
    for (int i = threadIdx.x; i < 64 * 31; i += 256) wl[i] = w[d0 * 31 + i];
    __syncthreads();
    int dl = threadIdx.x & 63, chunk = threadIdx.x >> 6;
    int d = d0 + dl;
    int s00 = s0 + chunk * 16;
    float wr[31];
#pragma unroll
    for (int t = 0; t < 31; ++t) wr[t] = wl[dl * 31 + t];
    float xw[46];
    const bf16* base = in + (size_t)(b * 4096) * 512 + d;
#pragma unroll
    for (int i = 0; i < 46; ++i) {
        int s = s00 - 15 + i;
        xw[i] = (s >= 0 && s < 4096) ? bf2f(base[(size_t)s * 512]) : 0.f;
    }
    float scv = bg[d] * rsqrtf(bvv[d] + 1e-5f);
    float wbd = wb[d], bmd = bm[d], bbd = bb2[d];
    bf16* op = out + (size_t)(b * 4096 + s00) * 512 + d;
#pragma unroll
    for (int j = 0; j < 16; ++j) {
        float acc = 0.f;
#pragma unroll
        for (int t = 0; t < 31; ++t) acc += wr[t] * xw[j + t];
        acc += wbd;
        acc = (acc - bmd) * scv + bbd;
        acc = acc / (1.f + __expf(-acc));
        op[(size_t)j * 512] = f2bf(acc);
    }
}

extern "C" void kernel_launch(void* const* d_in, const int* in_sizes, int n_in,
                              void* d_out, int out_size, void* d_ws, size_t ws_size,
                              hipStream_t stream) {
    (void)in_sizes; (void)n_in; (void)out_size; (void)ws_size;
    const float* x = (const float*)d_in[0];
    char* ws = (char*)d_ws;
    float* xf   = (float*)ws;                      // [0,32M)   fp32 residual
    bf16* ln_bf = (bf16*)(ws + 33554432);          // [32M,48M) LN output (bf16)
    bf16* h_bf  = (bf16*)(ws + 50331648);          // [48M,112M) hidden / q,k,v
    bf16* g_bf  = (bf16*)(ws + 117440512);         // [112M,128M) GLU out
    bf16* t_bf  = (bf16*)(ws + 134217728);         // [128M,144M) attn/conv out
    bf16* wc    = (bf16*)(ws + 150994944);         // [144M,...) transposed bf16 weights
    bf16 *qb = h_bf;
    bf16* w_f11 = wc;                // [2048][512]
    bf16* w_f12 = wc + 1048576;      // [512][2048]
    bf16* w_f21 = wc + 2097152;      // [2048][512]
    bf16* w_f22 = wc + 3145728;      // [512][2048]
    bf16* w_q   = wc + 4194304;      // [1536][512] fused qkv (contiguous)
    bf16* w_k   = wc + 4456448;
    bf16* w_v   = wc + 4718592;
    bf16* w_o   = wc + 4980736;      // [512][512]
    bf16* w_p1  = wc + 5242880;      // [1024][512]
    bf16* w_p2  = wc + 5767168;      // [512][512]

    // weight fp32 -> bf16 transposed [N][K]
    k_f2bt<<<dim3(64, 16), 256, 0, stream>>>((const float*)d_in[3],  w_f11, 512, 2048);
    k_f2bt<<<dim3(16, 64), 256, 0, stream>>>((const float*)d_in[5],  w_f12, 2048, 512);
    k_f2bt<<<dim3(64, 16), 256, 0, stream>>>((const float*)d_in[9],  w_f21, 512, 2048);
    k_f2bt<<<dim3(16, 64), 256, 0, stream>>>((const float*)d_in[11], w_f22, 2048, 512);
    k_f2bt<<<dim3(16, 16), 256, 0, stream>>>((const float*)d_in[15], w_q, 512, 512);
    k_f2bt<<<dim3(16, 16), 256, 0, stream>>>((const float*)d_in[16], w_k, 512, 512);
    k_f2bt<<<dim3(16, 16), 256, 0, stream>>>((const float*)d_in[17], w_v, 512, 512);
    k_f2bt<<<dim3(16, 16), 256, 0, stream>>>((const float*)d_in[18], w_o, 512, 512);
    k_f2bt<<<dim3(32, 16), 256, 0, stream>>>((const float*)d_in[26], w_p1, 512, 1024);
    k_f2bt<<<dim3(16, 16), 256, 0, stream>>>((const float*)d_in[34], w_p2, 512, 512);

    hipMemcpyAsync(xf, x, 33554432, hipMemcpyDeviceToDevice, stream);

    // FFN1: x += 0.5*FFN(LN(x))
    k_ln<true><<<16384, 64, 0, stream>>>(xf, (const float*)d_in[1], (const float*)d_in[2], ln_bf);
    k_gemm<1><<<dim3(16 * 128), 256, 0, stream>>>(ln_bf, w_f11, (const float*)d_in[4], h_bf, 16384, 2048, 512, 0.f, nullptr, nullptr, 16);
    k_gemm<4><<<dim3(4 * 128, 2), 256, 0, stream>>>(h_bf, w_f12, (const float*)d_in[6], xf, 16384, 512, 2048, 0.5f, nullptr, nullptr, 4);
    // attention (fused QKV)
    k_ln<true><<<16384, 64, 0, stream>>>(xf, (const float*)d_in[13], (const float*)d_in[14], ln_bf);
    k_gemm<3><<<dim3(12 * 128), 256, 0, stream>>>(ln_bf, w_q, (const float*)d_in[19], qb, 16384, 1536, 512, 0.f,
                                                  (const float*)d_in[20], (const float*)d_in[21], 12);
    k_attn<<<1024, 256, 0, stream>>>(qb, qb + 8388608, qb + 16777216, (const float*)d_in[23], t_bf);
    k_gemm<2><<<dim3(4 * 128), 256, 0, stream>>>(t_bf, w_o, (const float*)d_in[22], xf, 16384, 512, 512, 1.0f, nullptr, nullptr, 4);
    // conv module
    k_ln<true><<<16384, 64, 0, stream>>>(xf, (const float*)d_in[24], (const float*)d_in[25], ln_bf);
    k_gemm<0><<<dim3(8 * 128), 256, 0, stream>>>(ln_bf, w_p1, (const float*)d_in[27], h_bf, 16384, 1024, 512, 0.f, nullptr, nullptr, 8);
    k_glu<<<32768, 256, 0, stream>>>(h_bf, g_bf);
    k_conv<<<dim3(8, 64, 4), 256, 0, stream>>>(g_bf, (const float*)d_in[28], (const float*)d_in[29], (const float*)d_in[30],
                                               (const float*)d_in[31], (const float*)d_in[32], (const float*)d_in[33], t_bf);
    k_gemm<2><<<dim3(4 * 128), 256, 0, stream>>>(t_bf, w_p2, (const float*)d_in[35], xf, 16384, 512, 512, 1.0f, nullptr, nullptr, 4);
    // FFN2
    k_ln<true><<<16384, 64, 0, stream>>>(xf, (const float*)d_in[7], (const float*)d_in[8], ln_bf);
    k_gemm<1><<<dim3(16 * 128), 256, 0, stream>>>(ln_bf, w_f21, (const float*)d_in[10], h_bf, 16384, 2048, 512, 0.f, nullptr, nullptr, 16);
    k_gemm<4><<<dim3(4 * 128, 2), 256, 0, stream>>>(h_bf, w_f22, (const float*)d_in[12], xf, 16384, 512, 2048, 0.5f, nullptr, nullptr, 4);
    // final LN -> fp32 out
    k_ln<false><<<16384, 64, 0, stream>>>(xf, (const float*)d_in[36], (const float*)d_in[37], d_out);
}

// Round 8
// 684.827 us; speedup vs baseline: 1.1697x; 1.1697x over previous
//
#include <hip/hip_runtime.h>
#include <hip/hip_bf16.h>
#include <math.h>

// ConformerBlock on MI355X. B=4, S=4096, D=512, H=8, Hd=64, CTX=128, FFN=2048, KS=31.
// fp32 inputs/outputs. bf16 MFMA GEMMs (128-row tiles, TN=128/64 + global_load_lds +
// XCD-clustering swizzle), fused QKV, MFMA flash attention, tiled depthwise conv.

using bf16 = __hip_bfloat16;
typedef __bf16 bf16x8_t __attribute__((ext_vector_type(8)));
typedef float f32x4_t __attribute__((ext_vector_type(4)));

static __device__ __forceinline__ float bf2f(bf16 v) { return __bfloat162float(v); }
static __device__ __forceinline__ bf16 f2bf(float v) { return __float2bfloat16(v); }

#define GLOAD_LDS16(g, l)                                                            \
    __builtin_amdgcn_global_load_lds((const __attribute__((address_space(1))) void*)(g), \
                                     (__attribute__((address_space(3))) void*)(l), 16, 0, 0)

// ---------------- fp32 [K][N] -> bf16 transposed [N][K] ----------------
__global__ __launch_bounds__(256) void k_f2bt(const float* __restrict__ in, bf16* __restrict__ out,
                                              int K, int N) {
    __shared__ float t[32][33];
    int c = threadIdx.x & 31, r0 = threadIdx.x >> 5;
    int kb = blockIdx.y * 32, nb = blockIdx.x * 32;
#pragma unroll
    for (int i = 0; i < 4; ++i)
        t[r0 + i * 8][c] = in[(size_t)(kb + r0 + i * 8) * N + nb + c];
    __syncthreads();
#pragma unroll
    for (int i = 0; i < 4; ++i)
        out[(size_t)(nb + r0 + i * 8) * K + kb + c] = f2bf(t[c][r0 + i * 8]);
}

// ---------------- LayerNorm: fp32 in -> bf16 (or fp32) out, one wave per row ----------------
template <bool BF16OUT>
__global__ __launch_bounds__(64) void k_ln(const float* __restrict__ x, const float* __restrict__ g,
                                           const float* __restrict__ b, void* __restrict__ outp) {
    int row = blockIdx.x, t = threadIdx.x;
    const float* xr = x + (size_t)row * 512 + t * 8;
    float4 v0 = *(const float4*)xr;
    float4 v1 = *(const float4*)(xr + 4);
    float vals[8] = {v0.x, v0.y, v0.z, v0.w, v1.x, v1.y, v1.z, v1.w};
    float s = 0.f, ss = 0.f;
#pragma unroll
    for (int j = 0; j < 8; ++j) { s += vals[j]; ss += vals[j] * vals[j]; }
#pragma unroll
    for (int o = 32; o > 0; o >>= 1) { s += __shfl_xor(s, o, 64); ss += __shfl_xor(ss, o, 64); }
    float mean = s * (1.0f / 512.0f);
    float var  = ss * (1.0f / 512.0f) - mean * mean;
    float r = rsqrtf(var + 1e-5f);
    float4 g0 = *(const float4*)(g + t * 8);
    float4 g1 = *(const float4*)(g + t * 8 + 4);
    float4 b0 = *(const float4*)(b + t * 8);
    float4 b1 = *(const float4*)(b + t * 8 + 4);
    float gv[8] = {g0.x, g0.y, g0.z, g0.w, g1.x, g1.y, g1.z, g1.w};
    float bv[8] = {b0.x, b0.y, b0.z, b0.w, b1.x, b1.y, b1.z, b1.w};
    float ov[8];
#pragma unroll
    for (int j = 0; j < 8; ++j) ov[j] = (vals[j] - mean) * r * gv[j] + bv[j];
    if (BF16OUT) {
        union { uint4 u; bf16 h[8]; } oo;
#pragma unroll
        for (int j = 0; j < 8; ++j) oo.h[j] = f2bf(ov[j]);
        *(uint4*)((bf16*)outp + (size_t)row * 512 + t * 8) = oo.u;
    } else {
        float* op = (float*)outp + (size_t)row * 512 + t * 8;
        *(float4*)op = make_float4(ov[0], ov[1], ov[2], ov[3]);
        *(float4*)(op + 4) = make_float4(ov[4], ov[5], ov[6], ov[7]);
    }
}

// ---------------- GEMM: C = A[M,K] @ Bt[N,K]^T + bias, 128xTN tile, XCD swizzle ----------------
// 1D grid (nbx * 128 blocks); the nbx blocks sharing an A row-tile sit on consecutive
// slots of one XCD (id%8 -> XCD heuristic) so A re-reads hit that XCD's L2.
// MODE 0: bf16 store. MODE 1: exact GELU -> bf16. MODE 2: fp32 out = resid + scale*(acc+bias).
// MODE 3: QKV scatter (col/512 selects q/k/v buffer and bias from bias/b2/b3).
template <int MODE, int TN>
__global__ __launch_bounds__(256) void k_gemm(const bf16* __restrict__ A, const bf16* __restrict__ Bt,
                                              const float* __restrict__ bias, void* __restrict__ outp,
                                              int M, int N, int K, float scale,
                                              const float* __restrict__ b2, const float* __restrict__ b3,
                                              const float* __restrict__ resid, int nbx) {
    constexpr int NT = TN / 32;                 // B frags per wave
    __shared__ __align__(16) bf16 As[128 * 32];
    __shared__ __align__(16) bf16 Bs[TN * 32];
    int id = blockIdx.x;
    int xcd = id & 7, slot = id >> 3;
    int nbyg = (gridDim.x / nbx) >> 3;          // by-groups per XCD
    int bxi = slot % nbx;
    int byi = slot / nbx + xcd * nbyg;
    int bn = bxi * TN, bm = byi * 128;
    int tid = threadIdx.x, w = tid >> 6, l = tid & 63;
    int l15 = l & 15, quad = l >> 4;
    int wm = (w >> 1) * 64, wn = (w & 1) * (TN / 2);
    f32x4_t acc[4][NT] = {};
    const int brows = TN / 4;                   // B rows staged per wave
    const bf16* ag = A + (size_t)(bm + w * 32 + (l >> 2)) * K + (l & 3) * 8;
    const bf16* bg = Bt + (size_t)(bn + w * brows + (l >> 2)) * K + (l & 3) * 8;
    bf16* asl = As + w * 32 * 32;               // wave-uniform LDS bases
    bf16* bsl = Bs + w * brows * 32;

    for (int k0 = 0; k0 < K; k0 += 32) {
        __syncthreads();
#pragma unroll
        for (int j = 0; j < 2; ++j)
            GLOAD_LDS16(ag + (size_t)j * 16 * K + k0, asl + j * 16 * 32);
#pragma unroll
        for (int j = 0; j < TN / 64; ++j)
            GLOAD_LDS16(bg + (size_t)j * 16 * K + k0, bsl + j * 16 * 32);
        __syncthreads();
        bf16x8_t af[4], bfr[NT];
#pragma unroll
        for (int tm = 0; tm < 4; ++tm)
            af[tm] = *(const bf16x8_t*)(As + (wm + tm * 16 + l15) * 32 + quad * 8);
#pragma unroll
        for (int tn = 0; tn < NT; ++tn)
            bfr[tn] = *(const bf16x8_t*)(Bs + (wn + tn * 16 + l15) * 32 + quad * 8);
#pragma unroll
        for (int tm = 0; tm < 4; ++tm)
#pragma unroll
            for (int tn = 0; tn < NT; ++tn)
                acc[tm][tn] = __builtin_amdgcn_mfma_f32_16x16x32_bf16(af[tm], bfr[tn], acc[tm][tn], 0, 0, 0);
    }
#pragma unroll
    for (int tm = 0; tm < 4; ++tm)
#pragma unroll
        for (int tn = 0; tn < NT; ++tn) {
            int gcol = bn + wn + tn * 16 + l15;
            float bv;
            if (MODE == 3) {
                const float* bp = (gcol < 512) ? bias : (gcol < 1024 ? b2 : b3);
                bv = bp[gcol & 511];
            } else {
                bv = bias[gcol];
            }
#pragma unroll
            for (int r = 0; r < 4; ++r) {
                int grow = bm + wm + tm * 16 + quad * 4 + r;
                float vv = acc[tm][tn][r] + bv;
                if (MODE == 0) {
                    ((bf16*)outp)[(size_t)grow * N + gcol] = f2bf(vv);
                } else if (MODE == 1) {
                    float gl = 0.5f * vv * (1.0f + erff(vv * 0.70710678118654752f));
                    ((bf16*)outp)[(size_t)grow * N + gcol] = f2bf(gl);
                } else if (MODE == 2) {
                    size_t ix = (size_t)grow * N + gcol;
                    ((float*)outp)[ix] = resid[ix] + scale * vv;
                } else {
                    bf16* ob = (bf16*)outp + (size_t)(gcol >> 9) * 8388608;
                    ob[(size_t)grow * 512 + (gcol & 511)] = f2bf(vv);
                }
            }
        }
}

// ---------------- MFMA flash attention over 384-key windows ----------------
__global__ __launch_bounds__(256) void k_attn(const bf16* __restrict__ q, const bf16* __restrict__ k,
                                              const bf16* __restrict__ v, const float* __restrict__ rel_bias,
                                              bf16* __restrict__ out) {
    __shared__ __align__(16) bf16 Qs[128][72];
    __shared__ __align__(16) bf16 Ks[64][72];
    __shared__ __align__(16) bf16 Vt[64][72];
    __shared__ __align__(16) bf16 Pb[4][32][72];
    __shared__ float relb[257];
    int blk = blockIdx.x;
    int n = blk & 31, h = (blk >> 5) & 7, b = blk >> 8;
    int tid = threadIdx.x, w = tid >> 6, lane = tid & 63;
    int l15 = lane & 15, quad = lane >> 4;
    for (int i = tid; i < 257; i += 256) relb[i] = rel_bias[h * 257 + i];
    {
        const bf16* qg = q + (size_t)(b * 4096 + n * 128) * 512 + h * 64;
#pragma unroll
        for (int i = 0; i < 4; ++i) {
            int slot = tid + 256 * i;
            int row = slot >> 3, col = (slot & 7) * 8;
            *(uint4*)&Qs[row][col] = *(const uint4*)(qg + (size_t)row * 512 + col);
        }
    }
    float m_run[2][4], l_run[2][4];
#pragma unroll
    for (int qt = 0; qt < 2; ++qt)
#pragma unroll
        for (int r = 0; r < 4; ++r) { m_run[qt][r] = -1e30f; l_run[qt][r] = 0.f; }
    f32x4_t Oacc[2][4] = {};
    int kv0 = n * 128 - 128;
    for (int ch = 0; ch < 6; ++ch) {
        int kst = kv0 + ch * 64;
        if (kst < 0 || kst >= 4096) continue;
        __syncthreads();
        {
#pragma unroll
            for (int i = 0; i < 2; ++i) {
                int slot = tid + 256 * i;
                int row = slot >> 3, col = (slot & 7) * 8;
                *(uint4*)&Ks[row][col] = *(const uint4*)(k + (size_t)(b * 4096 + kst + row) * 512 + h * 64 + col);
            }
        }
        {
            int key = tid >> 2, c0 = (tid & 3) * 16;
            union { uint4 u[2]; bf16 hh[16]; } tv;
            const bf16* vg = v + (size_t)(b * 4096 + kst + key) * 512 + h * 64 + c0;
            tv.u[0] = *(const uint4*)vg;
            tv.u[1] = *(const uint4*)(vg + 8);
#pragma unroll
            for (int j = 0; j < 16; ++j) Vt[c0 + j][key] = tv.hh[j];
        }
        __syncthreads();
        bf16x8_t qf[2][2];
#pragma unroll
        for (int qt = 0; qt < 2; ++qt)
#pragma unroll
            for (int ks = 0; ks < 2; ++ks)
                qf[qt][ks] = *(const bf16x8_t*)&Qs[w * 32 + qt * 16 + l15][ks * 32 + quad * 8];
        float sc[2][4][4];
#pragma unroll
        for (int qt = 0; qt < 2; ++qt)
#pragma unroll
            for (int nt = 0; nt < 4; ++nt) {
                f32x4_t a = {};
#pragma unroll
                for (int ks = 0; ks < 2; ++ks) {
                    bf16x8_t kf = *(const bf16x8_t*)&Ks[nt * 16 + l15][ks * 32 + quad * 8];
                    a = __builtin_amdgcn_mfma_f32_16x16x32_bf16(qf[qt][ks], kf, a, 0, 0, 0);
                }
#pragma unroll
                for (int r = 0; r < 4; ++r) sc[qt][nt][r] = a[r];
            }
#pragma unroll
        for (int qt = 0; qt < 2; ++qt)
#pragma unroll
            for (int nt = 0; nt < 4; ++nt)
#pragma unroll
                for (int r = 0; r < 4; ++r) {
                    int qrow = w * 32 + qt * 16 + quad * 4 + r;
                    int rel = ch * 64 + nt * 16 + l15 - 128 - qrow;
                    int idx = rel + 128; idx = idx < 0 ? 0 : (idx > 256 ? 256 : idx);
                    float s = sc[qt][nt][r] * 0.125f + relb[idx];
                    sc[qt][nt][r] = (rel >= -128 && rel <= 128) ? s : -INFINITY;
                }
        float al[2][4];
#pragma unroll
        for (int qt = 0; qt < 2; ++qt)
#pragma unroll
            for (int r = 0; r < 4; ++r) {
                float mx = fmaxf(fmaxf(sc[qt][0][r], sc[qt][1][r]), fmaxf(sc[qt][2][r], sc[qt][3][r]));
#pragma unroll
                for (int mk = 1; mk <= 8; mk <<= 1) mx = fmaxf(mx, __shfl_xor(mx, mk, 64));
                float mn = fmaxf(m_run[qt][r], mx);
                float a = __expf(m_run[qt][r] - mn);
                float ps = 0.f;
#pragma unroll
                for (int nt = 0; nt < 4; ++nt) {
                    float p = __expf(sc[qt][nt][r] - mn);
                    sc[qt][nt][r] = p;
                    ps += p;
                }
#pragma unroll
                for (int mk = 1; mk <= 8; mk <<= 1) ps += __shfl_xor(ps, mk, 64);
                l_run[qt][r] = l_run[qt][r] * a + ps;
                m_run[qt][r] = mn;
                al[qt][r] = a;
            }
#pragma unroll
        for (int qt = 0; qt < 2; ++qt)
#pragma unroll
            for (int nt = 0; nt < 4; ++nt)
#pragma unroll
                for (int r = 0; r < 4; ++r)
                    Pb[w][qt * 16 + quad * 4 + r][nt * 16 + l15] = f2bf(sc[qt][nt][r]);
        __syncthreads();
#pragma unroll
        for (int qt = 0; qt < 2; ++qt) {
#pragma unroll
            for (int dt = 0; dt < 4; ++dt)
#pragma unroll
                for (int r = 0; r < 4; ++r)
                    Oacc[qt][dt][r] *= al[qt][r];
            bf16x8_t pf[2];
#pragma unroll
            for (int ks = 0; ks < 2; ++ks)
                pf[ks] = *(const bf16x8_t*)&Pb[w][qt * 16 + l15][ks * 32 + quad * 8];
#pragma unroll
            for (int dt = 0; dt < 4; ++dt) {
                f32x4_t a = Oacc[qt][dt];
#pragma unroll
                for (int ks = 0; ks < 2; ++ks) {
                    bf16x8_t vf = *(const bf16x8_t*)&Vt[dt * 16 + l15][ks * 32 + quad * 8];
                    a = __builtin_amdgcn_mfma_f32_16x16x32_bf16(pf[ks], vf, a, 0, 0, 0);
                }
                Oacc[qt][dt] = a;
            }
        }
    }
#pragma unroll
    for (int qt = 0; qt < 2; ++qt)
#pragma unroll
        for (int r = 0; r < 4; ++r) {
            float inv = 1.f / l_run[qt][r];
            int row = n * 128 + w * 32 + qt * 16 + quad * 4 + r;
#pragma unroll
            for (int dt = 0; dt < 4; ++dt)
                out[(size_t)(b * 4096 + row) * 512 + h * 64 + dt * 16 + l15] = f2bf(Oacc[qt][dt][r] * inv);
        }
}

// ---------------- GLU: [16384,1024] -> [16384,512], bf16 ----------------
__global__ __launch_bounds__(256) void k_glu(const bf16* __restrict__ h, bf16* __restrict__ out) {
    int idx = blockIdx.x * 256 + threadIdx.x;
    int m = idx >> 9, c = idx & 511;
    float a = bf2f(h[(size_t)m * 1024 + c]);
    float g = bf2f(h[(size_t)m * 1024 + c + 512]);
    out[idx] = f2bf(a / (1.f + __expf(-g)));
}

// ---------------- tiled depthwise conv (KS=31) + BN + SiLU ----------------
__global__ __launch_bounds__(256) void k_conv(const bf16* __restrict__ in, const float* __restrict__ w,
                                              const float* __restrict__ wb, const float* __restrict__ bg,
                                              const float* __restrict__ bb2, const float* __restrict__ bm,
                                              const float* __restrict__ bvv, bf16* __restrict__ out) {
    __shared__ float wl[64 * 31];
    int d0 = blockIdx.x * 64, s0 = blockIdx.y * 64, b = blockIdx.z;
    for (int i = threadIdx.x; i < 64 * 31; i += 256) wl[i] = w[d0 * 31 + i];
    __syncthreads();
    int dl = threadIdx.x & 63, chunk = threadIdx.x >> 6;
    int d = d0 + dl;
    int s00 = s0 + chunk * 16;
    float wr[31];
#pragma unroll
    for (int t = 0; t < 31; ++t) wr[t] = wl[dl * 31 + t];
    float xw[46];
    const bf16* base = in + (size_t)(b * 4096) * 512 + d;
#pragma unroll
    for (int i = 0; i < 46; ++i) {
        int s = s00 - 15 + i;
        xw[i] = (s >= 0 && s < 4096) ? bf2f(base[(size_t)s * 512]) : 0.f;
    }
    float scv = bg[d] * rsqrtf(bvv[d] + 1e-5f);
    float wbd = wb[d], bmd = bm[d], bbd = bb2[d];
    bf16* op = out + (size_t)(b * 4096 + s00) * 512 + d;
#pragma unroll
    for (int j = 0; j < 16; ++j) {
        float acc = 0.f;
#pragma unroll
        for (int t = 0; t < 31; ++t) acc += wr[t] * xw[j + t];
        acc += wbd;
        acc = (acc - bmd) * scv + bbd;
        acc = acc / (1.f + __expf(-acc));
        op[(size_t)j * 512] = f2bf(acc);
    }
}

extern "C" void kernel_launch(void* const* d_in, const int* in_sizes, int n_in,
                              void* d_out, int out_size, void* d_ws, size_t ws_size,
                              hipStream_t stream) {
    (void)in_sizes; (void)n_in; (void)out_size; (void)ws_size;
    const float* x = (const float*)d_in[0];
    char* ws = (char*)d_ws;
    float* xf   = (float*)ws;                      // [0,32M)   fp32 residual
    bf16* ln_bf = (bf16*)(ws + 33554432);          // [32M,48M) LN output (bf16)
    bf16* h_bf  = (bf16*)(ws + 50331648);          // [48M,112M) hidden / q,k,v
    bf16* g_bf  = (bf16*)(ws + 117440512);         // [112M,128M) GLU out
    bf16* t_bf  = (bf16*)(ws + 134217728);         // [128M,144M) attn/conv out
    bf16* wc    = (bf16*)(ws + 150994944);         // [144M,...) transposed bf16 weights
    bf16 *qb = h_bf;
    bf16* w_f11 = wc;                // [2048][512]
    bf16* w_f12 = wc + 1048576;      // [512][2048]
    bf16* w_f21 = wc + 2097152;      // [2048][512]
    bf16* w_f22 = wc + 3145728;      // [512][2048]
    bf16* w_q   = wc + 4194304;      // [1536][512] fused qkv (contiguous)
    bf16* w_k   = wc + 4456448;
    bf16* w_v   = wc + 4718592;
    bf16* w_o   = wc + 4980736;      // [512][512]
    bf16* w_p1  = wc + 5242880;      // [1024][512]
    bf16* w_p2  = wc + 5767168;      // [512][512]

    // weight fp32 -> bf16 transposed [N][K]
    k_f2bt<<<dim3(64, 16), 256, 0, stream>>>((const float*)d_in[3],  w_f11, 512, 2048);
    k_f2bt<<<dim3(16, 64), 256, 0, stream>>>((const float*)d_in[5],  w_f12, 2048, 512);
    k_f2bt<<<dim3(64, 16), 256, 0, stream>>>((const float*)d_in[9],  w_f21, 512, 2048);
    k_f2bt<<<dim3(16, 64), 256, 0, stream>>>((const float*)d_in[11], w_f22, 2048, 512);
    k_f2bt<<<dim3(16, 16), 256, 0, stream>>>((const float*)d_in[15], w_q, 512, 512);
    k_f2bt<<<dim3(16, 16), 256, 0, stream>>>((const float*)d_in[16], w_k, 512, 512);
    k_f2bt<<<dim3(16, 16), 256, 0, stream>>>((const float*)d_in[17], w_v, 512, 512);
    k_f2bt<<<dim3(16, 16), 256, 0, stream>>>((const float*)d_in[18], w_o, 512, 512);
    k_f2bt<<<dim3(32, 16), 256, 0, stream>>>((const float*)d_in[26], w_p1, 512, 1024);
    k_f2bt<<<dim3(16, 16), 256, 0, stream>>>((const float*)d_in[34], w_p2, 512, 512);

    // FFN1: xf = x + 0.5*FFN(LN(x))   (first LN reads x directly; no residual memcpy)
    k_ln<true><<<16384, 64, 0, stream>>>(x, (const float*)d_in[1], (const float*)d_in[2], ln_bf);
    k_gemm<1, 128><<<2048, 256, 0, stream>>>(ln_bf, w_f11, (const float*)d_in[4], h_bf, 16384, 2048, 512, 0.f, nullptr, nullptr, nullptr, 16);
    k_gemm<2, 64><<<1024, 256, 0, stream>>>(h_bf, w_f12, (const float*)d_in[6], xf, 16384, 512, 2048, 0.5f, nullptr, nullptr, x, 8);
    // attention (fused QKV)
    k_ln<true><<<16384, 64, 0, stream>>>(xf, (const float*)d_in[13], (const float*)d_in[14], ln_bf);
    k_gemm<3, 64><<<3072, 256, 0, stream>>>(ln_bf, w_q, (const float*)d_in[19], qb, 16384, 1536, 512, 0.f,
                                            (const float*)d_in[20], (const float*)d_in[21], nullptr, 24);
    k_attn<<<1024, 256, 0, stream>>>(qb, qb + 8388608, qb + 16777216, (const float*)d_in[23], t_bf);
    k_gemm<2, 64><<<1024, 256, 0, stream>>>(t_bf, w_o, (const float*)d_in[22], xf, 16384, 512, 512, 1.0f, nullptr, nullptr, xf, 8);
    // conv module
    k_ln<true><<<16384, 64, 0, stream>>>(xf, (const float*)d_in[24], (const float*)d_in[25], ln_bf);
    k_gemm<0, 64><<<2048, 256, 0, stream>>>(ln_bf, w_p1, (const float*)d_in[27], h_bf, 16384, 1024, 512, 0.f, nullptr, nullptr, nullptr, 16);
    k_glu<<<32768, 256, 0, stream>>>(h_bf, g_bf);
    k_conv<<<dim3(8, 64, 4), 256, 0, stream>>>(g_bf, (const float*)d_in[28], (const float*)d_in[29], (const float*)d_in[30],
                                               (const float*)d_in[31], (const float*)d_in[32], (const float*)d_in[33], t_bf);
    k_gemm<2, 64><<<1024, 256, 0, stream>>>(t_bf, w_p2, (const float*)d_in[35], xf, 16384, 512, 512, 1.0f, nullptr, nullptr, xf, 8);
    // FFN2
    k_ln<true><<<16384, 64, 0, stream>>>(xf, (const float*)d_in[7], (const float*)d_in[8], ln_bf);
    k_gemm<1, 128><<<2048, 256, 0, stream>>>(ln_bf, w_f21, (const float*)d_in[10], h_bf, 16384, 2048, 512, 0.f, nullptr, nullptr, nullptr, 16);
    k_gemm<2, 64><<<1024, 256, 0, stream>>>(h_bf, w_f22, (const float*)d_in[12], xf, 16384, 512, 2048, 0.5f, nullptr, nullptr, xf, 8);
    // final LN -> fp32 out
    k_ln<false><<<16384, 64, 0, stream>>>(xf, (const float*)d_in[36], (const float*)d_in[37], d_out);
}

// Round 9
// 677.110 us; speedup vs baseline: 1.1831x; 1.0114x over previous
//
#include <hip/hip_runtime.h>
#include <hip/hip_bf16.h>
#include <math.h>

// ConformerBlock on MI355X. B=4, S=4096, D=512, H=8, Hd=64, CTX=128, FFN=2048, KS=31.
// fp32 inputs/outputs. bf16 MFMA GEMMs (128-row tiles, TN=128/64, global_load_lds,
// XCD-clustering swizzle, LDS-transpose coalesced epilogue, fused GLU), fused QKV,
// MFMA flash attention, tiled depthwise conv. Residual fp32 in ws.

using bf16 = __hip_bfloat16;
typedef __bf16 bf16x8_t __attribute__((ext_vector_type(8)));
typedef float f32x4_t __attribute__((ext_vector_type(4)));

static __device__ __forceinline__ float bf2f(bf16 v) { return __bfloat162float(v); }
static __device__ __forceinline__ bf16 f2bf(float v) { return __float2bfloat16(v); }

#define GLOAD_LDS16(g, l)                                                            \
    __builtin_amdgcn_global_load_lds((const __attribute__((address_space(1))) void*)(g), \
                                     (__attribute__((address_space(3))) void*)(l), 16, 0, 0)

// ---------------- fused weight conversion: fp32 [K][N] -> bf16 [N][K] (10 matrices) ----
struct WSrcs { const float* s[10]; };
__global__ __launch_bounds__(256) void k_wconv(WSrcs srcs, bf16* __restrict__ wc) {
    // segment tables (block counts per matrix; 32x32 tiles)
    const int start[11] = {0, 1024, 2048, 3072, 4096, 4352, 4608, 4864, 5120, 5632, 5888};
    const int Ks[10]    = {512, 2048, 512, 2048, 512, 512, 512, 512, 512, 512};
    const int Ns[10]    = {2048, 512, 2048, 512, 512, 512, 512, 512, 1024, 512};
    const int doff[10]  = {0, 1048576, 2097152, 3145728, 4194304, 4456448, 4718592, 4980736, 5242880, 5767168};
    int id = blockIdx.x, seg = 0;
#pragma unroll
    for (int i = 1; i < 10; ++i) seg += (id >= start[i]);
    int lid = id - start[seg];
    int K = Ks[seg], N = Ns[seg];
    int nbx = N >> 5;
    int bx = lid % nbx, by = lid / nbx;
    int nb = bx * 32, kb = by * 32;
    const float* in = srcs.s[seg];
    bf16* out = wc + doff[seg];
    bool inter = (seg == 8);
    __shared__ float t[32][33];
    int c = threadIdx.x & 31, r0 = threadIdx.x >> 5;
#pragma unroll
    for (int i = 0; i < 4; ++i)
        t[r0 + i * 8][c] = in[(size_t)(kb + r0 + i * 8) * N + nb + c];
    __syncthreads();
#pragma unroll
    for (int i = 0; i < 4; ++i) {
        int n = nb + r0 + i * 8;
        int orow = inter ? ((n < 512) ? 2 * n : 2 * (n - 512) + 1) : n;
        out[(size_t)orow * K + kb + c] = f2bf(t[c][r0 + i * 8]);
    }
}

// ---------------- LayerNorm: 256 thr / 4 rows, one wave per row of 512 ----------------
template <bool BF16OUT>
__global__ __launch_bounds__(256) void k_ln(const float* __restrict__ x, const float* __restrict__ g,
                                            const float* __restrict__ b, void* __restrict__ outp) {
    int row = blockIdx.x * 4 + (threadIdx.x >> 6), t = threadIdx.x & 63;
    const float* xr = x + (size_t)row * 512 + t * 8;
    float4 v0 = *(const float4*)xr;
    float4 v1 = *(const float4*)(xr + 4);
    float vals[8] = {v0.x, v0.y, v0.z, v0.w, v1.x, v1.y, v1.z, v1.w};
    float s = 0.f, ss = 0.f;
#pragma unroll
    for (int j = 0; j < 8; ++j) { s += vals[j]; ss += vals[j] * vals[j]; }
#pragma unroll
    for (int o = 32; o > 0; o >>= 1) { s += __shfl_xor(s, o, 64); ss += __shfl_xor(ss, o, 64); }
    float mean = s * (1.0f / 512.0f);
    float var  = ss * (1.0f / 512.0f) - mean * mean;
    float r = rsqrtf(var + 1e-5f);
    float4 g0 = *(const float4*)(g + t * 8);
    float4 g1 = *(const float4*)(g + t * 8 + 4);
    float4 b0 = *(const float4*)(b + t * 8);
    float4 b1 = *(const float4*)(b + t * 8 + 4);
    float gv[8] = {g0.x, g0.y, g0.z, g0.w, g1.x, g1.y, g1.z, g1.w};
    float bv[8] = {b0.x, b0.y, b0.z, b0.w, b1.x, b1.y, b1.z, b1.w};
    float ov[8];
#pragma unroll
    for (int j = 0; j < 8; ++j) ov[j] = (vals[j] - mean) * r * gv[j] + bv[j];
    if (BF16OUT) {
        union { uint4 u; bf16 h[8]; } oo;
#pragma unroll
        for (int j = 0; j < 8; ++j) oo.h[j] = f2bf(ov[j]);
        *(uint4*)((bf16*)outp + (size_t)row * 512 + t * 8) = oo.u;
    } else {
        float* op = (float*)outp + (size_t)row * 512 + t * 8;
        *(float4*)op = make_float4(ov[0], ov[1], ov[2], ov[3]);
        *(float4*)(op + 4) = make_float4(ov[4], ov[5], ov[6], ov[7]);
    }
}

// ---------------- GEMM: C = A[M,K] @ Bt[N,K]^T + bias, 128xTN tile, XCD swizzle ----------------
// MODE 0: bf16 store. MODE 1: exact GELU -> bf16. MODE 2: fp32 out = resid + scale*(acc+bias).
// MODE 3: QKV scatter. MODE 5: fused GLU (interleaved a/gate cols) -> bf16 [M][N/2].
// Epilogue: per-wave LDS transpose (reusing As) -> 16B/lane full-line stores.
template <int MODE, int TN>
__global__ __launch_bounds__(256) void k_gemm(const bf16* __restrict__ A, const bf16* __restrict__ Bt,
                                              const float* __restrict__ bias, void* __restrict__ outp,
                                              int M, int N, int K, float scale,
                                              const float* __restrict__ b2, const float* __restrict__ b3,
                                              const float* __restrict__ resid, int nbx) {
    constexpr int NT = TN / 32;                 // B frags per wave
    __shared__ __align__(16) bf16 As[128 * 32];
    __shared__ __align__(16) bf16 Bs[TN * 32];
    int id = blockIdx.x;
    int xcd = id & 7, slot = id >> 3;
    int nbyg = (gridDim.x / nbx) >> 3;
    int bxi = slot % nbx;
    int byi = slot / nbx + xcd * nbyg;
    int bn = bxi * TN, bm = byi * 128;
    int tid = threadIdx.x, w = tid >> 6, l = tid & 63;
    int l15 = l & 15, quad = l >> 4;
    int wm = (w >> 1) * 64, wn = (w & 1) * (TN / 2);
    f32x4_t acc[4][NT] = {};
    const int brows = TN / 4;
    const bf16* ag = A + (size_t)(bm + w * 32 + (l >> 2)) * K + (l & 3) * 8;
    const bf16* bg = Bt + (size_t)(bn + w * brows + (l >> 2)) * K + (l & 3) * 8;
    bf16* asl = As + w * 32 * 32;
    bf16* bsl = Bs + w * brows * 32;

    for (int k0 = 0; k0 < K; k0 += 32) {
        __syncthreads();
#pragma unroll
        for (int j = 0; j < 2; ++j)
            GLOAD_LDS16(ag + (size_t)j * 16 * K + k0, asl + j * 16 * 32);
#pragma unroll
        for (int j = 0; j < TN / 64; ++j)
            GLOAD_LDS16(bg + (size_t)j * 16 * K + k0, bsl + j * 16 * 32);
        __syncthreads();
        bf16x8_t af[4], bfr[NT];
#pragma unroll
        for (int tm = 0; tm < 4; ++tm)
            af[tm] = *(const bf16x8_t*)(As + (wm + tm * 16 + l15) * 32 + quad * 8);
#pragma unroll
        for (int tn = 0; tn < NT; ++tn)
            bfr[tn] = *(const bf16x8_t*)(Bs + (wn + tn * 16 + l15) * 32 + quad * 8);
#pragma unroll
        for (int tm = 0; tm < 4; ++tm)
#pragma unroll
            for (int tn = 0; tn < NT; ++tn)
                acc[tm][tn] = __builtin_amdgcn_mfma_f32_16x16x32_bf16(af[tm], bfr[tn], acc[tm][tn], 0, 0, 0);
    }
    // -------- coalesced epilogue via per-wave LDS transpose (reuse As: 4 x 2KB) --------
    __syncthreads();
    float* tb = (float*)As + w * 512;           // 16 rows x 32 floats per wave
#pragma unroll
    for (int tm = 0; tm < 4; ++tm)
#pragma unroll
        for (int cp = 0; cp < NT / 2; ++cp) {
#pragma unroll
            for (int j = 0; j < 2; ++j)
#pragma unroll
                for (int r = 0; r < 4; ++r)
                    tb[(quad * 4 + r) * 32 + j * 16 + l15] = acc[tm][2 * cp + j][r];
            // read back row-major: lane -> row l>>2, cols (l&3)*8 .. +8
            int lr = l >> 2, lc = (l & 3) * 8;
            float v[8];
#pragma unroll
            for (int i = 0; i < 8; ++i) v[i] = tb[lr * 32 + lc + i];
            int gr = bm + wm + tm * 16 + lr;
            int gc = bn + wn + cp * 32 + lc;
            if (MODE == 0 || MODE == 1) {
                union { uint4 u; bf16 h[8]; } oo;
#pragma unroll
                for (int i = 0; i < 8; ++i) {
                    float vv = v[i] + bias[gc + i];
                    if (MODE == 1) vv = 0.5f * vv * (1.0f + erff(vv * 0.70710678118654752f));
                    oo.h[i] = f2bf(vv);
                }
                *(uint4*)((bf16*)outp + (size_t)gr * N + gc) = oo.u;
            } else if (MODE == 2) {
                size_t ix = (size_t)gr * N + gc;
                float4 r0 = *(const float4*)(resid + ix);
                float4 r1 = *(const float4*)(resid + ix + 4);
                float rr[8] = {r0.x, r0.y, r0.z, r0.w, r1.x, r1.y, r1.z, r1.w};
                float o[8];
#pragma unroll
                for (int i = 0; i < 8; ++i) o[i] = rr[i] + scale * (v[i] + bias[gc + i]);
                *(float4*)((float*)outp + ix) = make_float4(o[0], o[1], o[2], o[3]);
                *(float4*)((float*)outp + ix + 4) = make_float4(o[4], o[5], o[6], o[7]);
            } else if (MODE == 3) {
                const float* bp = (gc < 512) ? bias : (gc < 1024 ? b2 : b3);
                int cc = gc & 511;
                union { uint4 u; bf16 h[8]; } oo;
#pragma unroll
                for (int i = 0; i < 8; ++i) oo.h[i] = f2bf(v[i] + bp[cc + i]);
                bf16* ob = (bf16*)outp + (size_t)(gc >> 9) * 8388608;
                *(uint4*)(ob + (size_t)gr * 512 + cc) = oo.u;
            } else {                             // MODE 5: GLU, interleaved pairs in-lane
                union { ushort4 u; bf16 h[4]; } oo;
#pragma unroll
                for (int p = 0; p < 4; ++p) {
                    int ic = gc + 2 * p;         // even: a (orig col ic/2), odd: gate (+512)
                    float a = v[2 * p] + bias[ic >> 1];
                    float gt = v[2 * p + 1] + bias[(ic >> 1) + 512];
                    oo.h[p] = f2bf(a / (1.f + __expf(-gt)));
                }
                *(ushort4*)((bf16*)outp + (size_t)gr * (N >> 1) + (gc >> 1)) = oo.u;
            }
        }
}

// ---------------- MFMA flash attention over 384-key windows ----------------
__global__ __launch_bounds__(256) void k_attn(const bf16* __restrict__ q, const bf16* __restrict__ k,
                                              const bf16* __restrict__ v, const float* __restrict__ rel_bias,
                                              bf16* __restrict__ out) {
    __shared__ __align__(16) bf16 Qs[128][72];
    __shared__ __align__(16) bf16 Ks[64][72];
    __shared__ __align__(16) bf16 Vt[64][72];
    __shared__ __align__(16) bf16 Pb[4][32][72];
    __shared__ float relb[257];
    int blk = blockIdx.x;
    int n = blk & 31, h = (blk >> 5) & 7, b = blk >> 8;
    int tid = threadIdx.x, w = tid >> 6, lane = tid & 63;
    int l15 = lane & 15, quad = lane >> 4;
    for (int i = tid; i < 257; i += 256) relb[i] = rel_bias[h * 257 + i];
    {
        const bf16* qg = q + (size_t)(b * 4096 + n * 128) * 512 + h * 64;
#pragma unroll
        for (int i = 0; i < 4; ++i) {
            int slot = tid + 256 * i;
            int row = slot >> 3, col = (slot & 7) * 8;
            *(uint4*)&Qs[row][col] = *(const uint4*)(qg + (size_t)row * 512 + col);
        }
    }
    float m_run[2][4], l_run[2][4];
#pragma unroll
    for (int qt = 0; qt < 2; ++qt)
#pragma unroll
        for (int r = 0; r < 4; ++r) { m_run[qt][r] = -1e30f; l_run[qt][r] = 0.f; }
    f32x4_t Oacc[2][4] = {};
    int kv0 = n * 128 - 128;
    for (int ch = 0; ch < 6; ++ch) {
        int kst = kv0 + ch * 64;
        if (kst < 0 || kst >= 4096) continue;
        __syncthreads();
        {
#pragma unroll
            for (int i = 0; i < 2; ++i) {
                int slot = tid + 256 * i;
                int row = slot >> 3, col = (slot & 7) * 8;
                *(uint4*)&Ks[row][col] = *(const uint4*)(k + (size_t)(b * 4096 + kst + row) * 512 + h * 64 + col);
            }
        }
        {
            int key = tid >> 2, c0 = (tid & 3) * 16;
            union { uint4 u[2]; bf16 hh[16]; } tv;
            const bf16* vg = v + (size_t)(b * 4096 + kst + key) * 512 + h * 64 + c0;
            tv.u[0] = *(const uint4*)vg;
            tv.u[1] = *(const uint4*)(vg + 8);
#pragma unroll
            for (int j = 0; j < 16; ++j) Vt[c0 + j][key] = tv.hh[j];
        }
        __syncthreads();
        bf16x8_t qf[2][2];
#pragma unroll
        for (int qt = 0; qt < 2; ++qt)
#pragma unroll
            for (int ks = 0; ks < 2; ++ks)
                qf[qt][ks] = *(const bf16x8_t*)&Qs[w * 32 + qt * 16 + l15][ks * 32 + quad * 8];
        float sc[2][4][4];
#pragma unroll
        for (int qt = 0; qt < 2; ++qt)
#pragma unroll
            for (int nt = 0; nt < 4; ++nt) {
                f32x4_t a = {};
#pragma unroll
                for (int ks = 0; ks < 2; ++ks) {
                    bf16x8_t kf = *(const bf16x8_t*)&Ks[nt * 16 + l15][ks * 32 + quad * 8];
                    a = __builtin_amdgcn_mfma_f32_16x16x32_bf16(qf[qt][ks], kf, a, 0, 0, 0);
                }
#pragma unroll
                for (int r = 0; r < 4; ++r) sc[qt][nt][r] = a[r];
            }
#pragma unroll
        for (int qt = 0; qt < 2; ++qt)
#pragma unroll
            for (int nt = 0; nt < 4; ++nt)
#pragma unroll
                for (int r = 0; r < 4; ++r) {
                    int qrow = w * 32 + qt * 16 + quad * 4 + r;
                    int rel = ch * 64 + nt * 16 + l15 - 128 - qrow;
                    int idx = rel + 128; idx = idx < 0 ? 0 : (idx > 256 ? 256 : idx);
                    float s = sc[qt][nt][r] * 0.125f + relb[idx];
                    sc[qt][nt][r] = (rel >= -128 && rel <= 128) ? s : -INFINITY;
                }
        float al[2][4];
#pragma unroll
        for (int qt = 0; qt < 2; ++qt)
#pragma unroll
            for (int r = 0; r < 4; ++r) {
                float mx = fmaxf(fmaxf(sc[qt][0][r], sc[qt][1][r]), fmaxf(sc[qt][2][r], sc[qt][3][r]));
#pragma unroll
                for (int mk = 1; mk <= 8; mk <<= 1) mx = fmaxf(mx, __shfl_xor(mx, mk, 64));
                float mn = fmaxf(m_run[qt][r], mx);
                float a = __expf(m_run[qt][r] - mn);
                float ps = 0.f;
#pragma unroll
                for (int nt = 0; nt < 4; ++nt) {
                    float p = __expf(sc[qt][nt][r] - mn);
                    sc[qt][nt][r] = p;
                    ps += p;
                }
#pragma unroll
                for (int mk = 1; mk <= 8; mk <<= 1) ps += __shfl_xor(ps, mk, 64);
                l_run[qt][r] = l_run[qt][r] * a + ps;
                m_run[qt][r] = mn;
                al[qt][r] = a;
            }
#pragma unroll
        for (int qt = 0; qt < 2; ++qt)
#pragma unroll
            for (int nt = 0; nt < 4; ++nt)
#pragma unroll
                for (int r = 0; r < 4; ++r)
                    Pb[w][qt * 16 + quad * 4 + r][nt * 16 + l15] = f2bf(sc[qt][nt][r]);
        __syncthreads();
#pragma unroll
        for (int qt = 0; qt < 2; ++qt) {
#pragma unroll
            for (int dt = 0; dt < 4; ++dt)
#pragma unroll
                for (int r = 0; r < 4; ++r)
                    Oacc[qt][dt][r] *= al[qt][r];
            bf16x8_t pf[2];
#pragma unroll
            for (int ks = 0; ks < 2; ++ks)
                pf[ks] = *(const bf16x8_t*)&Pb[w][qt * 16 + l15][ks * 32 + quad * 8];
#pragma unroll
            for (int dt = 0; dt < 4; ++dt) {
                f32x4_t a = Oacc[qt][dt];
#pragma unroll
                for (int ks = 0; ks < 2; ++ks) {
                    bf16x8_t vf = *(const bf16x8_t*)&Vt[dt * 16 + l15][ks * 32 + quad * 8];
                    a = __builtin_amdgcn_mfma_f32_16x16x32_bf16(pf[ks], vf, a, 0, 0, 0);
                }
                Oacc[qt][dt] = a;
            }
        }
    }
#pragma unroll
    for (int qt = 0; qt < 2; ++qt)
#pragma unroll
        for (int r = 0; r < 4; ++r) {
            float inv = 1.f / l_run[qt][r];
            int row = n * 128 + w * 32 + qt * 16 + quad * 4 + r;
#pragma unroll
            for (int dt = 0; dt < 4; ++dt)
                out[(size_t)(b * 4096 + row) * 512 + h * 64 + dt * 16 + l15] = f2bf(Oacc[qt][dt][r] * inv);
        }
}

// ---------------- tiled depthwise conv (KS=31) + BN + SiLU ----------------
__global__ __launch_bounds__(256) void k_conv(const bf16* __restrict__ in, const float* __restrict__ w,
                                              const float* __restrict__ wb, const float* __restrict__ bg,
                                              const float* __restrict__ bb2, const float* __restrict__ bm,
                                              const float* __restrict__ bvv, bf16* __restrict__ out) {
    __shared__ float wl[64 * 31];
    int d0 = blockIdx.x * 64, s0 = blockIdx.y * 64, b = blockIdx.z;
    for (int i = threadIdx.x; i < 64 * 31; i += 256) wl[i] = w[d0 * 31 + i];
    __syncthreads();
    int dl = threadIdx.x & 63, chunk = threadIdx.x >> 6;
    int d = d0 + dl;
    int s00 = s0 + chunk * 16;
    float wr[31];
#pragma unroll
    for (int t = 0; t < 31; ++t) wr[t] = wl[dl * 31 + t];
    float xw[46];
    const bf16* base = in + (size_t)(b * 4096) * 512 + d;
#pragma unroll
    for (int i = 0; i < 46; ++i) {
        int s = s00 - 15 + i;
        xw[i] = (s >= 0 && s < 4096) ? bf2f(base[(size_t)s * 512]) : 0.f;
    }
    float scv = bg[d] * rsqrtf(bvv[d] + 1e-5f);
    float wbd = wb[d], bmd = bm[d], bbd = bb2[d];
    bf16* op = out + (size_t)(b * 4096 + s00) * 512 + d;
#pragma unroll
    for (int j = 0; j < 16; ++j) {
        float acc = 0.f;
#pragma unroll
        for (int t = 0; t < 31; ++t) acc += wr[t] * xw[j + t];
        acc += wbd;
        acc = (acc - bmd) * scv + bbd;
        acc = acc / (1.f + __expf(-acc));
        op[(size_t)j * 512] = f2bf(acc);
    }
}

extern "C" void kernel_launch(void* const* d_in, const int* in_sizes, int n_in,
                              void* d_out, int out_size, void* d_ws, size_t ws_size,
                              hipStream_t stream) {
    (void)in_sizes; (void)n_in; (void)out_size; (void)ws_size;
    const float* x = (const float*)d_in[0];
    char* ws = (char*)d_ws;
    float* xf   = (float*)ws;                      // [0,32M)   fp32 residual
    bf16* ln_bf = (bf16*)(ws + 33554432);          // [32M,48M) LN output (bf16)
    bf16* h_bf  = (bf16*)(ws + 50331648);          // [48M,112M) hidden / q,k,v
    bf16* g_bf  = (bf16*)(ws + 117440512);         // [112M,128M) GLU out
    bf16* t_bf  = (bf16*)(ws + 134217728);         // [128M,144M) attn/conv out
    bf16* wc    = (bf16*)(ws + 150994944);         // [144M,...) converted bf16 weights
    bf16 *qb = h_bf;
    bf16* w_f11 = wc;                // [2048][512]
    bf16* w_f12 = wc + 1048576;      // [512][2048]
    bf16* w_f21 = wc + 2097152;      // [2048][512]
    bf16* w_f22 = wc + 3145728;      // [512][2048]
    bf16* w_q   = wc + 4194304;      // [1536][512] fused qkv (contiguous)
    bf16* w_o   = wc + 4980736;      // [512][512]
    bf16* w_p1  = wc + 5242880;      // [1024][512] interleaved a/gate rows
    bf16* w_p2  = wc + 5767168;      // [512][512]

    // fused weight conversion (10 matrices, one launch)
    WSrcs srcs;
    srcs.s[0] = (const float*)d_in[3];  srcs.s[1] = (const float*)d_in[5];
    srcs.s[2] = (const float*)d_in[9];  srcs.s[3] = (const float*)d_in[11];
    srcs.s[4] = (const float*)d_in[15]; srcs.s[5] = (const float*)d_in[16];
    srcs.s[6] = (const float*)d_in[17]; srcs.s[7] = (const float*)d_in[18];
    srcs.s[8] = (const float*)d_in[26]; srcs.s[9] = (const float*)d_in[34];
    k_wconv<<<5888, 256, 0, stream>>>(srcs, wc);

    // FFN1: xf = x + 0.5*FFN(LN(x))
    k_ln<true><<<4096, 256, 0, stream>>>(x, (const float*)d_in[1], (const float*)d_in[2], ln_bf);
    k_gemm<1, 128><<<2048, 256, 0, stream>>>(ln_bf, w_f11, (const float*)d_in[4], h_bf, 16384, 2048, 512, 0.f, nullptr, nullptr, nullptr, 16);
    k_gemm<2, 64><<<1024, 256, 0, stream>>>(h_bf, w_f12, (const float*)d_in[6], xf, 16384, 512, 2048, 0.5f, nullptr, nullptr, x, 8);
    // attention (fused QKV)
    k_ln<true><<<4096, 256, 0, stream>>>(xf, (const float*)d_in[13], (const float*)d_in[14], ln_bf);
    k_gemm<3, 64><<<3072, 256, 0, stream>>>(ln_bf, w_q, (const float*)d_in[19], qb, 16384, 1536, 512, 0.f,
                                            (const float*)d_in[20], (const float*)d_in[21], nullptr, 24);
    k_attn<<<1024, 256, 0, stream>>>(qb, qb + 8388608, qb + 16777216, (const float*)d_in[23], t_bf);
    k_gemm<2, 64><<<1024, 256, 0, stream>>>(t_bf, w_o, (const float*)d_in[22], xf, 16384, 512, 512, 1.0f, nullptr, nullptr, xf, 8);
    // conv module (pw1 + fused GLU)
    k_ln<true><<<4096, 256, 0, stream>>>(xf, (const float*)d_in[24], (const float*)d_in[25], ln_bf);
    k_gemm<5, 64><<<2048, 256, 0, stream>>>(ln_bf, w_p1, (const float*)d_in[27], g_bf, 16384, 1024, 512, 0.f, nullptr, nullptr, nullptr, 16);
    k_conv<<<dim3(8, 64, 4), 256, 0, stream>>>(g_bf, (const float*)d_in[28], (const float*)d_in[29], (const float*)d_in[30],
                                               (const float*)d_in[31], (const float*)d_in[32], (const float*)d_in[33], t_bf);
    k_gemm<2, 64><<<1024, 256, 0, stream>>>(t_bf, w_p2, (const float*)d_in[35], xf, 16384, 512, 512, 1.0f, nullptr, nullptr, xf, 8);
    // FFN2
    k_ln<true><<<4096, 256, 0, stream>>>(xf, (const float*)d_in[7], (const float*)d_in[8], ln_bf);
    k_gemm<1, 128><<<2048, 256, 0, stream>>>(ln_bf, w_f21, (const float*)d_in[10], h_bf, 16384, 2048, 512, 0.f, nullptr, nullptr, nullptr, 16);
    k_gemm<2, 64><<<1024, 256, 0, stream>>>(h_bf, w_f22, (const float*)d_in[12], xf, 16384, 512, 2048, 0.5f, nullptr, nullptr, xf, 8);
    // final LN -> fp32 out
    k_ln<false><<<4096, 256, 0, stream>>>(xf, (const float*)d_in[36], (const float*)d_in[37], d_out);
}